// Round 4
// baseline (710.116 us; speedup 1.0000x reference)
//
#include <hip/hip_runtime.h>
#include <math.h>

#define Hd 128
#define Wd 128
#define HW 16384

__device__ __forceinline__ float wred(float v) {
  #pragma unroll
  for (int o = 32; o > 0; o >>= 1) v += __shfl_down(v, o, 64);
  return v;
}

// ---- K12 fused: grouped 3x3 key conv (in-register) + e1 + e2 + c1 + GN partials.
// grid (64 tiles, B=8, s=2), block 256 (16x16 px, 1 px/thread).
// R4: force the register allocator's occupancy target DOWN via LDS size.
// R2/R3 post-mortem: allocator kept a 64-VGPR budget (8 waves/EU target, LDS only
// 14 KB -> 11 blocks/CU possible) and spilled the 48 accumulators to scratch
// (WRITE 70->201 MB). amdgpu_waves_per_eu(4,4) was silently ignored.
// Fix: double-buffered halo tile xt[2][10][18][24] = 34.6 KB LDS -> max 4 blocks/CU
// (hard physical limit) -> allocator budget 512/4 = 128 VGPR -> ~90 live floats fit.
// Double buffer also cuts barriers to 1/group and overlaps staging with compute.
// Channels 8,9 of each buffer are padding (occupancy control only).
__global__ __launch_bounds__(256) void k_fused(const float* __restrict__ x,
                                               const float* __restrict__ wkey,
                                               const float* __restrict__ we1,
                                               const float* __restrict__ we2,
                                               const float* __restrict__ be2,
                                               const float* __restrict__ wc1,
                                               float* __restrict__ xv,
                                               float* __restrict__ wpre,
                                               float* __restrict__ spart) {
  __shared__ float xt[2][10][18][24];  // 2 buffers, 8 used ch + 2 pad ch, rows 18, cols padded to 24
  __shared__ float sred2[4][8];
  const int tid = threadIdx.x;
  const int tx = tid & 15, ty = tid >> 4;  // 16x16 tile
  const int b = blockIdx.y, s = blockIdx.z;
  const int h0 = (blockIdx.x >> 3) * 16, w0 = (blockIdx.x & 7) * 16;
  const int p = ((h0 + ty) << 7) + (w0 + tx);
  float c1acc[32], e1acc[16];
  #pragma unroll
  for (int o = 0; o < 32; ++o) c1acc[o] = 0.f;
  #pragma unroll
  for (int o = 0; o < 16; ++o) e1acc[o] = 0.f;

  // stage 8 channels (32s+8g .. +7) with 18x18 halo into buffer `buf`
  auto stage = [&](int buf, int g) {
    const int cb = b * 64 + 32 * s + 8 * g;
    for (int i = tid; i < 8 * 324; i += 256) {
      int ch = i / 324, r = i - ch * 324;
      int yy = r / 18, xx = r - yy * 18;
      int gh = h0 + yy - 1, gw = w0 + xx - 1;
      float v = 0.f;
      if (gh >= 0 && gh < Hd && gw >= 0 && gw < Wd)
        v = x[((long)(cb + ch) << 14) + (gh << 7) + gw];
      xt[buf][ch][yy][xx] = v;
    }
  };

  stage(0, 0);
  #pragma unroll
  for (int g = 0; g < 4; ++g) {
    __syncthreads();  // staged(g) visible; all threads done computing g-1
    if (g < 3) stage((g + 1) & 1, g + 1);  // prefetch next group into other buffer
    const int cur = g & 1;
    float kacc[8] = {0.f, 0.f, 0.f, 0.f, 0.f, 0.f, 0.f, 0.f};
    float xcg[8];
    const float* wg = wkey + (4 * s + g) * 576;  // 8 oc x 72 weights, wave-uniform
    #pragma unroll
    for (int ich = 0; ich < 8; ++ich) {
      float nb[9];
      #pragma unroll
      for (int rr = 0; rr < 3; ++rr)
        #pragma unroll
        for (int cc = 0; cc < 3; ++cc)
          nb[rr * 3 + cc] = xt[cur][ich][ty + rr][tx + cc];
      xcg[ich] = nb[4];  // center = own pixel
      #pragma unroll
      for (int oc = 0; oc < 8; ++oc) {
        const float* wr = wg + oc * 72 + ich * 9;
        #pragma unroll
        for (int k9 = 0; k9 < 9; ++k9) kacc[oc] += wr[k9] * nb[k9];
      }
    }
    // fold this group's x/k channels into the 1x1-conv accumulators, then drop them
    #pragma unroll
    for (int jj = 0; jj < 8; ++jj) {
      const int j = 8 * g + jj;
      const float xcv = xcg[jj];
      const float kcv = fmaxf(kacc[jj], 0.f);
      #pragma unroll
      for (int o = 0; o < 32; ++o) c1acc[o] += wc1[(32 * s + o) * 32 + j] * xcv;
      #pragma unroll
      for (int o = 0; o < 16; ++o)
        e1acc[o] += we1[(16 * s + o) * 64 + 2 * j] * xcv +
                    we1[(16 * s + o) * 64 + 2 * j + 1] * kcv;
    }
  }
  // value path: store grouped 1x1 conv results (32->32 per half)
  #pragma unroll 4
  for (int o = 0; o < 32; ++o)
    xv[((long)(b * 64 + 32 * s + o) << 14) + p] = c1acc[o];
  // e1 ReLU
  float w1a[16];
  #pragma unroll
  for (int o = 0; o < 16; ++o) w1a[o] = fmaxf(e1acc[o], 0.f);
  // e2: 16 -> 36 (+bias), store w_pre, GN sum/sumsq partials
  #pragma unroll
  for (int gl = 0; gl < 4; ++gl) {
    float lgs = 0.f, lgq = 0.f;
    #pragma unroll
    for (int kk = 0; kk < 9; ++kk) {
      const int oc2 = 36 * s + gl * 9 + kk;
      const float* wr = we2 + oc2 * 16;
      float a = be2[oc2];
      #pragma unroll
      for (int ic = 0; ic < 16; ++ic) a += wr[ic] * w1a[ic];
      wpre[((long)(b * 72 + oc2) << 14) + p] = a;
      lgs += a;
      lgq += a * a;
    }
    float r1 = wred(lgs), r2 = wred(lgq);
    if ((tid & 63) == 0) {
      sred2[tid >> 6][2 * gl] = r1;
      sred2[tid >> 6][2 * gl + 1] = r2;
    }
  }
  __syncthreads();
  if (tid < 8) {
    float a = sred2[0][tid] + sred2[1][tid] + sred2[2][tid] + sred2[3][tid];
    spart[blockIdx.x * 128 + b * 16 + s * 8 + tid] = a;
  }
}

// ---- K3: reduce spart columns + finalize GN stats. 1 block x 128 threads ----
__global__ void k_gnstat(const float* __restrict__ spart, float* __restrict__ minv) {
  __shared__ float sred[128];
  const int t = threadIdx.x;  // 128
  float a = 0.f;
  #pragma unroll 8
  for (int r = 0; r < 64; ++r) a += spart[r * 128 + t];
  sred[t] = a;
  __syncthreads();
  if (t < 64) {
    const float N = 9.f * (float)HW;
    float s = sred[2 * t], q = sred[2 * t + 1];
    float m = s / N;
    float var = q / N - m * m;
    minv[2 * t] = m;
    minv[2 * t + 1] = rsqrtf(var + 1e-5f);
  }
}

// ---- K4: per-pixel local 3x3 conv + CA partials. grid (8,4,64), 2 vertical px/thread
// part layout: [row=128][ch=512], row = (by*8+bx)*4 + wave.
__global__ __launch_bounds__(256) void k_local(const float* __restrict__ kxv,
                                               const float* __restrict__ wpre,
                                               const float* __restrict__ minv,
                                               const float* __restrict__ gnw,
                                               const float* __restrict__ gnb,
                                               float* __restrict__ out,
                                               float* __restrict__ part) {
  __shared__ float xt[8][34][24];
  const int tid = threadIdx.x;
  const int tx = tid & 15, ty = tid >> 4;
  const int z = blockIdx.z;
  const int b2 = z >> 2, g = z & 3;
  const int t = b2 & 1, b = b2 >> 1;
  const int h0 = blockIdx.y * 32, w0 = blockIdx.x * 16;
  for (int i = tid; i < 8 * 612; i += 256) {
    int ch = i / 612, r = i - ch * 612;
    int yy = r / 18, xx = r - yy * 18;
    int gh = h0 + yy - 1, gw = w0 + xx - 1;
    float v = 0.f;
    if (gh >= 0 && gh < Hd && gw >= 0 && gw < Wd)
      v = kxv[((long)(b2 * 32 + g * 8 + ch) << 14) + (gh << 7) + gw];
    xt[ch][yy][xx] = v;
  }
  __syncthreads();
  const int gg = 4 * t + g;
  const float m = minv[(b * 8 + gg) * 2];
  const float inv = minv[(b * 8 + gg) * 2 + 1];
  const int p0 = ((h0 + 2 * ty) << 7) + (w0 + tx);
  const int p1 = p0 + 128;
  float wn0[9], wn1[9];
  #pragma unroll
  for (int kk = 0; kk < 9; ++kk) {
    const int ch72 = 36 * t + 9 * g + kk;
    const long base = ((long)(b * 72 + ch72) << 14);
    const float sc = inv * gnw[ch72], sh = gnb[ch72] - m * inv * gnw[ch72];
    wn0[kk] = wpre[base + p0] * sc + sh;
    wn1[kk] = wpre[base + p1] * sc + sh;
  }
  const int prow = (blockIdx.y * 8 + blockIdx.x) * 4 + (tid >> 6);
  #pragma unroll
  for (int cc = 0; cc < 8; ++cc) {
    float nb[12];
    #pragma unroll
    for (int rr = 0; rr < 4; ++rr)
      #pragma unroll
      for (int ccol = 0; ccol < 3; ++ccol)
        nb[rr * 3 + ccol] = xt[cc][2 * ty + rr][tx + ccol];
    float o0 = 0.f, o1 = 0.f;
    #pragma unroll
    for (int dy = 0; dy < 3; ++dy)
      #pragma unroll
      for (int dx = 0; dx < 3; ++dx) {
        o0 += wn0[dy * 3 + dx] * nb[dy * 3 + dx];
        o1 += wn1[dy * 3 + dx] * nb[(dy + 1) * 3 + dx];
      }
    const int ch512 = b2 * 32 + g * 8 + cc;
    out[((long)ch512 << 14) + p0] = o0;
    out[((long)ch512 << 14) + p1] = o1;
    float os = wred(o0 + o1);
    if ((tid & 63) == 0) part[prow * 512 + ch512] = os;
  }
}

// ---- K5: reduce CA partials + SE MLP (64 -> 4 relu -> 64 sigmoid). 1 block x 512 ----
__global__ void k_ca(const float* __restrict__ part, const float* __restrict__ du1,
                     const float* __restrict__ du2, float* __restrict__ ys) {
  __shared__ float sy[8][64];
  __shared__ float sy4[8][4];
  const int tid = threadIdx.x;  // 512
  const int b = tid >> 6, c = tid & 63;
  float acc = 0.f;
  #pragma unroll 8
  for (int r = 0; r < 128; ++r) acc += part[r * 512 + tid];
  sy[b][c] = acc * (1.f / (float)HW);
  __syncthreads();
  if (tid < 32) {
    int bb = tid >> 2, j = tid & 3;
    float a = 0.f;
    for (int c2 = 0; c2 < 64; ++c2) a += sy[bb][c2] * du1[j * 64 + c2];
    sy4[bb][j] = fmaxf(a, 0.f);
  }
  __syncthreads();
  float z = 0.f;
  #pragma unroll
  for (int j = 0; j < 4; ++j) z += sy4[b][j] * du2[c * 4 + j];
  ys[tid] = 1.f / (1.f + expf(-z));
}

// ---- K6: scale output by channel-attention gate ----
__global__ __launch_bounds__(256) void k_scale(float* __restrict__ out,
                                               const float* __restrict__ ys) {
  const long i4 = (long)blockIdx.x * 256 + threadIdx.x;  // float4 index
  const long e = i4 * 4;
  const int bc = (int)(e >> 14);  // b*64+c
  const float s = ys[bc];
  float4* o = (float4*)out;
  float4 v = o[i4];
  v.x *= s; v.y *= s; v.z *= s; v.w *= s;
  o[i4] = v;
}

extern "C" void kernel_launch(void* const* d_in, const int* in_sizes, int n_in,
                              void* d_out, int out_size, void* d_ws, size_t ws_size,
                              hipStream_t stream) {
  const float* x    = (const float*)d_in[0];
  const float* wkey = (const float*)d_in[1];
  const float* we1  = (const float*)d_in[2];
  const float* we2  = (const float*)d_in[3];
  const float* be2  = (const float*)d_in[4];
  const float* gnw  = (const float*)d_in[5];
  const float* gnb  = (const float*)d_in[6];
  const float* wc1  = (const float*)d_in[7];
  const float* du1  = (const float*)d_in[8];
  const float* du2  = (const float*)d_in[9];
  float* out = (float*)d_out;
  float* ws = (float*)d_ws;

  float* kxv  = ws;                    // 8*64*HW floats (xv only; k never hits HBM)
  float* wpre = ws + 8388608;          // 8*72*HW floats
  float* part = ws + 17825792;         // spart [64][128] / part [128][512] overlay
  float* spart = part;                 //   (disjoint lifetimes)
  float* minv = part + 131072;         // 128 floats
  float* ys   = minv + 128;            // 512 floats

  k_fused<<<dim3(64, 8, 2), 256, 0, stream>>>(x, wkey, we1, we2, be2, wc1, kxv, wpre, spart);
  k_gnstat<<<1, 128, 0, stream>>>(spart, minv);
  k_local<<<dim3(8, 4, 64), 256, 0, stream>>>(kxv, wpre, minv, gnw, gnb, out, part);
  k_ca<<<1, 512, 0, stream>>>(part, du1, du2, ys);
  k_scale<<<8192, 256, 0, stream>>>(out, ys);
}

// Round 6
// 230.781 us; speedup vs baseline: 3.0770x; 3.0770x over previous
//
#include <hip/hip_runtime.h>
#include <math.h>

#define Hd 128
#define Wd 128
#define HW 16384

__device__ __forceinline__ float wred(float v) {
  #pragma unroll
  for (int o = 32; o > 0; o >>= 1) v += __shfl_down(v, o, 64);
  return v;
}

// ---- K12 fused: grouped 3x3 key conv (in-register) + e1 + e2 + c1 + GN partials.
// grid (64 tiles, B=8, s=2), block 256 (16x16 px, 1 px/thread).
// R6 = R5 resubmit (infra failure) + race fix: spart no longer overlays part,
// since k_local now both READS spart (GN finalize) and WRITES part (CA partials);
// overlay was safe only when k_gnstat consumed spart in between.
// Structure = R1 (93us best codegen); pixel-major xv [b][p][64] / wpre [b][p][72].
__global__ __launch_bounds__(256) void k_fused(const float* __restrict__ x,
                                               const float* __restrict__ wkey,
                                               const float* __restrict__ we1,
                                               const float* __restrict__ we2,
                                               const float* __restrict__ be2,
                                               const float* __restrict__ wc1,
                                               float* __restrict__ xv,
                                               float* __restrict__ wpre,
                                               float* __restrict__ spart) {
  __shared__ float xt[8][18][24];
  __shared__ float sred2[4][8];
  const int tid = threadIdx.x;
  const int tx = tid & 15, ty = tid >> 4;  // 16x16 tile
  const int b = blockIdx.y, s = blockIdx.z;
  const int h0 = (blockIdx.x >> 3) * 16, w0 = (blockIdx.x & 7) * 16;
  const int p = ((h0 + ty) << 7) + (w0 + tx);
  float xc[32], kc[32];
  for (int g = 0; g < 4; ++g) {
    // stage 8 channels (32s+8g .. +7) with 18x18 halo, rows padded to 24
    for (int i = tid; i < 8 * 324; i += 256) {
      int ch = i / 324, r = i - ch * 324;
      int yy = r / 18, xx = r - yy * 18;
      int gh = h0 + yy - 1, gw = w0 + xx - 1;
      float v = 0.f;
      if (gh >= 0 && gh < Hd && gw >= 0 && gw < Wd)
        v = x[((long)(b * 64 + 32 * s + 8 * g + ch) << 14) + (gh << 7) + gw];
      xt[ch][yy][xx] = v;
    }
    __syncthreads();
    float kacc[8] = {0.f, 0.f, 0.f, 0.f, 0.f, 0.f, 0.f, 0.f};
    const float* wg = wkey + (4 * s + g) * 576;  // 8 oc x 72 weights, wave-uniform
    #pragma unroll
    for (int ich = 0; ich < 8; ++ich) {
      float nb[9];
      #pragma unroll
      for (int rr = 0; rr < 3; ++rr)
        #pragma unroll
        for (int cc = 0; cc < 3; ++cc)
          nb[rr * 3 + cc] = xt[ich][ty + rr][tx + cc];
      xc[8 * g + ich] = nb[4];  // center = own pixel
      #pragma unroll
      for (int oc = 0; oc < 8; ++oc) {
        const float* wr = wg + oc * 72 + ich * 9;
        #pragma unroll
        for (int k9 = 0; k9 < 9; ++k9) kacc[oc] += wr[k9] * nb[k9];
      }
    }
    #pragma unroll
    for (int oc = 0; oc < 8; ++oc) kc[8 * g + oc] = fmaxf(kacc[oc], 0.f);
    __syncthreads();  // before next group's staging overwrites
  }
  // value path: grouped 1x1 conv (32->32 per half), pixel-major xv, float4 stores
  float* xvp = xv + ((long)(b * HW + p)) * 64 + 32 * s;  // 128B-aligned
  #pragma unroll
  for (int o4 = 0; o4 < 8; ++o4) {
    float va[4];
    #pragma unroll
    for (int oo = 0; oo < 4; ++oo) {
      const float* wr = wc1 + (32 * s + 4 * o4 + oo) * 32;
      float a = 0.f;
      #pragma unroll
      for (int j = 0; j < 32; ++j) a += wr[j] * xc[j];
      va[oo] = a;
    }
    ((float4*)xvp)[o4] = make_float4(va[0], va[1], va[2], va[3]);
  }
  // e1: 64(interleaved x,k) -> 16, ReLU
  float w1a[16];
  #pragma unroll
  for (int o = 0; o < 16; ++o) {
    const float* wr = we1 + (16 * s + o) * 64;
    float a = 0.f;
    #pragma unroll
    for (int j = 0; j < 32; ++j) a += wr[2 * j] * xc[j] + wr[2 * j + 1] * kc[j];
    w1a[o] = fmaxf(a, 0.f);
  }
  // e2: 16 -> 36 (+bias), pixel-major wpre (9 const-offset stores per gl),
  // per-wave GN sum/sumsq partials
  float* wpp = wpre + ((long)(b * HW + p)) * 72 + 36 * s;
  #pragma unroll
  for (int gl = 0; gl < 4; ++gl) {
    float lgs = 0.f, lgq = 0.f;
    #pragma unroll
    for (int kk = 0; kk < 9; ++kk) {
      const int oc2 = 36 * s + gl * 9 + kk;
      const float* wr = we2 + oc2 * 16;
      float a = be2[oc2];
      #pragma unroll
      for (int ic = 0; ic < 16; ++ic) a += wr[ic] * w1a[ic];
      wpp[gl * 9 + kk] = a;
      lgs += a;
      lgq += a * a;
    }
    float r1 = wred(lgs), r2 = wred(lgq);
    if ((tid & 63) == 0) {
      sred2[tid >> 6][2 * gl] = r1;
      sred2[tid >> 6][2 * gl + 1] = r2;
    }
  }
  __syncthreads();
  if (tid < 8) {
    float a = sred2[0][tid] + sred2[1][tid] + sred2[2][tid] + sred2[3][tid];
    spart[blockIdx.x * 128 + b * 16 + s * 8 + tid] = a;
  }
}

// ---- K4: per-pixel local 3x3 conv + CA partials + inline GN-stat finalize.
// grid (8,4,64), 2 vertical px/thread. Wave 0 reduces the 64 spart partials for
// this block's (b,gg); xv/wpre read via pixel-major layouts.
// part layout: [row=128][ch=512], row = (by*8+bx)*4 + wave.
__global__ __launch_bounds__(256) void k_local(const float* __restrict__ xv,
                                               const float* __restrict__ wpre,
                                               const float* __restrict__ spart,
                                               const float* __restrict__ gnw,
                                               const float* __restrict__ gnb,
                                               float* __restrict__ out,
                                               float* __restrict__ part) {
  __shared__ float xt[8][34][24];
  __shared__ float sminv[2];
  const int tid = threadIdx.x;
  const int tx = tid & 15, ty = tid >> 4;
  const int z = blockIdx.z;
  const int b2 = z >> 2, g = z & 3;
  const int t = b2 & 1, b = b2 >> 1;
  const int gg = 4 * t + g;
  const int h0 = blockIdx.y * 32, w0 = blockIdx.x * 16;
  // stage 8 xv channels (32t+8g..+7) with halo, from pixel-major xv: 2 float4/px
  for (int i = tid; i < 612; i += 256) {
    int yy = i / 18, xx = i - yy * 18;
    int gh = h0 + yy - 1, gw = w0 + xx - 1;
    float4 v0 = make_float4(0.f, 0.f, 0.f, 0.f), v1 = v0;
    if (gh >= 0 && gh < Hd && gw >= 0 && gw < Wd) {
      const float4* src = (const float4*)(xv + ((long)(b * HW) + (gh << 7) + gw) * 64 +
                                          32 * t + 8 * g);  // 32B-aligned
      v0 = src[0];
      v1 = src[1];
    }
    xt[0][yy][xx] = v0.x; xt[1][yy][xx] = v0.y; xt[2][yy][xx] = v0.z; xt[3][yy][xx] = v0.w;
    xt[4][yy][xx] = v1.x; xt[5][yy][xx] = v1.y; xt[6][yy][xx] = v1.z; xt[7][yy][xx] = v1.w;
  }
  // GN stat finalize for this block's group (wave 0): sum 64 tile-partials
  if (tid < 64) {
    const float* sp = spart + tid * 128 + (b * 8 + gg) * 2;
    float sv = sp[0], qv = sp[1];
    #pragma unroll
    for (int o = 32; o > 0; o >>= 1) {
      sv += __shfl_down(sv, o, 64);
      qv += __shfl_down(qv, o, 64);
    }
    if (tid == 0) {
      const float N = 9.f * (float)HW;
      float mm = sv / N;
      float var = qv / N - mm * mm;
      sminv[0] = mm;
      sminv[1] = rsqrtf(var + 1e-5f);
    }
  }
  __syncthreads();
  const float m = sminv[0];
  const float inv = sminv[1];
  const int p0 = ((h0 + 2 * ty) << 7) + (w0 + tx);
  const int p1 = p0 + 128;
  // per-pixel kernel weights from pixel-major wpre: 9 const-offset loads per px
  const float* w0p = wpre + ((long)(b * HW + p0)) * 72 + 36 * t + 9 * g;
  const float* w1p = wpre + ((long)(b * HW + p1)) * 72 + 36 * t + 9 * g;
  float wn0[9], wn1[9];
  #pragma unroll
  for (int kk = 0; kk < 9; ++kk) {
    const int ch72 = 36 * t + 9 * g + kk;
    const float sc = inv * gnw[ch72], sh = gnb[ch72] - m * inv * gnw[ch72];
    wn0[kk] = w0p[kk] * sc + sh;
    wn1[kk] = w1p[kk] * sc + sh;
  }
  const int prow = (blockIdx.y * 8 + blockIdx.x) * 4 + (tid >> 6);
  #pragma unroll
  for (int cc = 0; cc < 8; ++cc) {
    float nb[12];
    #pragma unroll
    for (int rr = 0; rr < 4; ++rr)
      #pragma unroll
      for (int ccol = 0; ccol < 3; ++ccol)
        nb[rr * 3 + ccol] = xt[cc][2 * ty + rr][tx + ccol];
    float o0 = 0.f, o1 = 0.f;
    #pragma unroll
    for (int dy = 0; dy < 3; ++dy)
      #pragma unroll
      for (int dx = 0; dx < 3; ++dx) {
        o0 += wn0[dy * 3 + dx] * nb[dy * 3 + dx];
        o1 += wn1[dy * 3 + dx] * nb[(dy + 1) * 3 + dx];
      }
    const int ch512 = b2 * 32 + g * 8 + cc;
    out[((long)ch512 << 14) + p0] = o0;
    out[((long)ch512 << 14) + p1] = o1;
    float os = wred(o0 + o1);
    if ((tid & 63) == 0) part[prow * 512 + ch512] = os;
  }
}

// ---- K5: reduce CA partials + SE MLP (64 -> 4 relu -> 64 sigmoid). 1 block x 512 ----
__global__ void k_ca(const float* __restrict__ part, const float* __restrict__ du1,
                     const float* __restrict__ du2, float* __restrict__ ys) {
  __shared__ float sy[8][64];
  __shared__ float sy4[8][4];
  const int tid = threadIdx.x;  // 512
  const int b = tid >> 6, c = tid & 63;
  float acc = 0.f;
  #pragma unroll 8
  for (int r = 0; r < 128; ++r) acc += part[r * 512 + tid];
  sy[b][c] = acc * (1.f / (float)HW);
  __syncthreads();
  if (tid < 32) {
    int bb = tid >> 2, j = tid & 3;
    float a = 0.f;
    for (int c2 = 0; c2 < 64; ++c2) a += sy[bb][c2] * du1[j * 64 + c2];
    sy4[bb][j] = fmaxf(a, 0.f);
  }
  __syncthreads();
  float z = 0.f;
  #pragma unroll
  for (int j = 0; j < 4; ++j) z += sy4[b][j] * du2[c * 4 + j];
  ys[tid] = 1.f / (1.f + expf(-z));
}

// ---- K6: scale output by channel-attention gate ----
__global__ __launch_bounds__(256) void k_scale(float* __restrict__ out,
                                               const float* __restrict__ ys) {
  const long i4 = (long)blockIdx.x * 256 + threadIdx.x;  // float4 index
  const long e = i4 * 4;
  const int bc = (int)(e >> 14);  // b*64+c
  const float s = ys[bc];
  float4* o = (float4*)out;
  float4 v = o[i4];
  v.x *= s; v.y *= s; v.z *= s; v.w *= s;
  o[i4] = v;
}

extern "C" void kernel_launch(void* const* d_in, const int* in_sizes, int n_in,
                              void* d_out, int out_size, void* d_ws, size_t ws_size,
                              hipStream_t stream) {
  const float* x    = (const float*)d_in[0];
  const float* wkey = (const float*)d_in[1];
  const float* we1  = (const float*)d_in[2];
  const float* we2  = (const float*)d_in[3];
  const float* be2  = (const float*)d_in[4];
  const float* gnw  = (const float*)d_in[5];
  const float* gnb  = (const float*)d_in[6];
  const float* wc1  = (const float*)d_in[7];
  const float* du1  = (const float*)d_in[8];
  const float* du2  = (const float*)d_in[9];
  float* out = (float*)d_out;
  float* ws = (float*)d_ws;

  float* xv   = ws;                    // 8*64*HW floats, pixel-major [b][p][64]
  float* wpre = ws + 8388608;          // 8*72*HW floats, pixel-major [b][p][72]
  float* part = ws + 17825792;         // [128][512] CA partials
  float* spart = part + 65536;         // [64][128] GN partials (disjoint from part!)
  float* ys   = spart + 8192;          // 512 floats

  k_fused<<<dim3(64, 8, 2), 256, 0, stream>>>(x, wkey, we1, we2, be2, wc1, xv, wpre, spart);
  k_local<<<dim3(8, 4, 64), 256, 0, stream>>>(xv, wpre, spart, gnw, gnb, out, part);
  k_ca<<<1, 512, 0, stream>>>(part, du1, du2, ys);
  k_scale<<<8192, 256, 0, stream>>>(out, ys);
}